// Round 6
// baseline (571.937 us; speedup 1.0000x reference)
//
#include <hip/hip_runtime.h>

// Problem constants (from reference)
constexpr int Kk   = 21;
constexpr int Hh   = 512, Ww = 512;
constexpr int HO   = 492, WO = 492;          // valid conv output dims
constexpr int Cc   = 10;                     // center offset
constexpr int CTRi = 220;                    // center channel idx (dropped)
constexpr int NCH  = 440;                    // K*K - 1
constexpr int ROW4 = WO / 4;                 // 123 float4 per w row (exact, 16B aligned)
constexpr int N4F  = Hh * Ww / 4;            // 65,536 float4s for fidelity

constexpr int PLANE4 = HO * ROW4;            // 60,516 float4 per w channel plane
constexpr int SPLITS = 6;                    // row-splits per plane (492 = 6*82)
constexpr int RPS    = HO / SPLITS;          // 82 rows per block
constexpr int CHUNK4 = RPS * ROW4;           // 10,086 float4 per block (contiguous!)
constexpr int NBLK   = NCH * SPLITS;         // 2640 blocks

constexpr float SCALE_S  = (float)((512.0 * 512.0 * 128.0) / (440.0 * 492.0 * 492.0));
constexpr float FID_RATIO = (float)((1.0 / (512.0 * 512.0)) /
                                    ((512.0 * 512.0 * 128.0) / (440.0 * 492.0 * 492.0)));

typedef float floatx4  __attribute__((ext_vector_type(4)));              // 16B aligned
typedef float floatx4u __attribute__((ext_vector_type(4), aligned(4)));  // unaligned-ok

#define TPB 256

__device__ __forceinline__ float block_reduce_256(float v) {
    #pragma unroll
    for (int off = 32; off; off >>= 1) v += __shfl_down(v, off, 64);
    __shared__ float smem[TPB / 64];
    const int lane = threadIdx.x & 63;
    const int wid  = threadIdx.x >> 6;
    if (lane == 0) smem[wid] = v;
    __syncthreads();
    float r = 0.f;
    if (threadIdx.x == 0) {
        #pragma unroll
        for (int k = 0; k < TPB / 64; ++k) r += smem[k];
    }
    return r;
}

// One block = one channel n x 82 contiguous w rows: the w-stream per block is
// a single sequential 161 KB run (DRAM page friendly), nt-hinted (no L2/L3
// pollution; r5 showed nt is worth ~26 us). n block-uniform -> bias/ki/kj
// scalar. Center+neighbor taps come from L1/L2-resident outp rows.
__global__ __launch_bounds__(TPB) void main_kernel(
        const float* __restrict__ outp,
        const float* __restrict__ targ,
        const float* __restrict__ w,
        const float* __restrict__ bias,
        float* __restrict__ partial)
{
    const int t = threadIdx.x;
    float acc = 0.f;

    // ---- fused fidelity: first N4F global threads take one float4 each ----
    {
        const int fq = blockIdx.x * TPB + t;
        if (fq < N4F) {
            const floatx4 a  = ((const floatx4*)outp)[fq];
            const floatx4 tg = ((const floatx4*)targ)[fq];
            const float d0 = a.x - tg.x, d1 = a.y - tg.y,
                        d2 = a.z - tg.z, d3 = a.w - tg.w;
            acc = (d0 * d0 + d1 * d1 + d2 * d2 + d3 * d3) * FID_RATIO;
        }
    }

    // ---- smooth term ----
    const int n  = blockIdx.x / SPLITS;            // channel (block-uniform)
    const int s  = blockIdx.x - n * SPLITS;        // row-split
    const int kk = n + (n >= CTRi ? 1 : 0);        // skip dropped center chan
    const int ki = kk / Kk;
    const int kj = kk - ki * Kk;
    const float b = bias[n];

    const floatx4* wplane = (const floatx4*)w + (long)n * PLANE4;
    const int lo = s * CHUNK4;
    const int hi = lo + CHUNK4;

    float a0 = 0.f, a1 = 0.f, a2 = 0.f, a3 = 0.f;
    for (int idx = lo + t; idx < hi; idx += TPB) {
        const int r   = idx / ROW4;                // magic-mul (const divisor)
        const int col = (idx - r * ROW4) * 4;

        const floatx4  w4 = __builtin_nontemporal_load(wplane + idx);
        const floatx4u c4 = *(const floatx4u*)(outp + (r + Cc) * Ww + (Cc + col));
        const floatx4u n4 = *(const floatx4u*)(outp + (r + ki) * Ww + (kj + col));

        const float d0 = c4.x - n4.x + b;
        const float d1 = c4.y - n4.y + b;
        const float d2 = c4.z - n4.z + b;
        const float d3 = c4.w - n4.w + b;

        a0 += w4.x * d0 * d0;
        a1 += w4.y * d1 * d1;
        a2 += w4.z * d2 * d2;
        a3 += w4.w * d3 * d3;
    }
    acc += (a0 + a1) + (a2 + a3);

    const float bsum = block_reduce_256(acc);
    if (t == 0) partial[blockIdx.x] = bsum;
}

__global__ __launch_bounds__(TPB) void finalize_kernel(
        const float* __restrict__ partial,
        float* __restrict__ out)
{
    float v = 0.f;
    for (int idx = threadIdx.x; idx < NBLK; idx += TPB) v += partial[idx];
    const float s = block_reduce_256(v);
    if (threadIdx.x == 0) out[0] = s * SCALE_S;
}

extern "C" void kernel_launch(void* const* d_in, const int* in_sizes, int n_in,
                              void* d_out, int out_size, void* d_ws, size_t ws_size,
                              hipStream_t stream) {
    const float* outp = (const float*)d_in[0];   // output (512,512)
    const float* targ = (const float*)d_in[1];   // target (512,512)
    const float* w    = (const float*)d_in[2];   // w_ij (440,492,492)
    const float* bias = (const float*)d_in[3];   // bias (440,)

    float* partial = (float*)d_ws;               // NBLK partials

    main_kernel<<<NBLK, TPB, 0, stream>>>(outp, targ, w, bias, partial);
    finalize_kernel<<<1, TPB, 0, stream>>>(partial, (float*)d_out);
}

// Round 7
// 524.230 us; speedup vs baseline: 1.0910x; 1.0910x over previous
//
#include <hip/hip_runtime.h>

// Problem constants (from reference)
constexpr int Kk   = 21;
constexpr int Hh   = 512, Ww = 512;
constexpr int HO   = 492, WO = 492;          // valid conv output dims
constexpr int Cc   = 10;                     // center offset
constexpr int CTRi = 220;                    // center channel idx (dropped)
constexpr int NCH  = 440;                    // K*K - 1
constexpr int ROW4 = WO / 4;                 // 123 float4 per w row (exact, 16B aligned)
constexpr int N4F  = Hh * Ww / 4;            // 65,536 float4s for fidelity

constexpr int RSPLIT = HO / 2;               // 246 row-blocks, 2 rows each
constexpr int CSPLIT = 8;                    // channel splits
constexpr int NPB    = NCH / CSPLIT;         // 55 channels per block
constexpr int NBLK   = RSPLIT * CSPLIT;      // 1968 blocks

constexpr float SCALE_S  = (float)((512.0 * 512.0 * 128.0) / (440.0 * 492.0 * 492.0));
constexpr float FID_RATIO = (float)((1.0 / (512.0 * 512.0)) /
                                    ((512.0 * 512.0 * 128.0) / (440.0 * 492.0 * 492.0)));

typedef float floatx4  __attribute__((ext_vector_type(4)));              // 16B aligned
typedef float floatx4u __attribute__((ext_vector_type(4), aligned(4)));  // unaligned-ok

#define TPB 256

__device__ __forceinline__ float block_reduce_256(float v) {
    #pragma unroll
    for (int off = 32; off; off >>= 1) v += __shfl_down(v, off, 64);
    __shared__ float smem[TPB / 64];
    const int lane = threadIdx.x & 63;
    const int wid  = threadIdx.x >> 6;
    if (lane == 0) smem[wid] = v;
    __syncthreads();
    float r = 0.f;
    if (threadIdx.x == 0) {
        #pragma unroll
        for (int k = 0; k < TPB / 64; ++k) r += smem[k];
    }
    return r;
}

// Best-known config (r4): one block = 2 output rows x 55 channels.
//  - w-stream: nt-hinted dwordx4 (r5 proved nt is worth ~26 us: dead stream,
//    don't allocate in L2/L3)
//  - interleaved block layout (r6's sequential-per-block variant regressed 48 us)
//  - n block-uniform -> bias/kj/ki scalarize; center taps register-resident
//  - neighbor taps: ONE unaligned dwordx4 from L1/L2-resident outp rows
__global__ __launch_bounds__(TPB) void main_kernel(
        const float* __restrict__ outp,
        const float* __restrict__ targ,
        const float* __restrict__ w,
        const float* __restrict__ bias,
        float* __restrict__ partial)
{
    const int t = threadIdx.x;
    float acc = 0.f;

    // ---- fused fidelity: first N4F global threads take one float4 each ----
    {
        const int fq = blockIdx.x * TPB + t;
        if (fq < N4F) {
            const floatx4 a  = ((const floatx4*)outp)[fq];
            const floatx4 tg = ((const floatx4*)targ)[fq];
            const float d0 = a.x - tg.x, d1 = a.y - tg.y,
                        d2 = a.z - tg.z, d3 = a.w - tg.w;
            acc = (d0 * d0 + d1 * d1 + d2 * d2 + d3 * d3) * FID_RATIO;
        }
    }

    // ---- smooth term ----
    const int rowblk = blockIdx.x % RSPLIT;
    const int csplit = blockIdx.x / RSPLIT;
    const int n0     = csplit * NPB;

    if (t < 2 * ROW4) {                       // 246 active threads
        const int di = (t >= ROW4) ? 1 : 0;
        const int j4 = t - di * ROW4;
        const int i  = rowblk * 2 + di;       // w-plane row
        const int j  = 4 * j4;                // w-plane col (float units)

        // center taps: invariant over all channels
        const float* crow = outp + (i + Cc) * Ww + (Cc + j);
        const float c0 = crow[0], c1 = crow[1], c2 = crow[2], c3 = crow[3];

        const float* obase = outp + i * Ww + j;    // + ki*Ww + kj gives neighbor
        const floatx4* wp  = (const floatx4*)w + ((long)(n0 * HO + i) * ROW4 + j4);

        float a0 = 0.f, a1 = 0.f, a2 = 0.f, a3 = 0.f;
        #pragma unroll 5
        for (int n = n0; n < n0 + NPB; ++n, wp += HO * ROW4) {
            const int kk = n + (n >= CTRi ? 1 : 0);   // skip dropped center chan
            const int ki = kk / Kk;
            const int kj = kk - ki * Kk;

            const floatx4  w4 = __builtin_nontemporal_load(wp);
            const float    b  = bias[n];                              // uniform
            const floatx4u n4 = *(const floatx4u*)(obase + ki * Ww + kj);

            const float d0 = c0 - n4.x + b;
            const float d1 = c1 - n4.y + b;
            const float d2 = c2 - n4.z + b;
            const float d3 = c3 - n4.w + b;

            a0 += w4.x * d0 * d0;
            a1 += w4.y * d1 * d1;
            a2 += w4.z * d2 * d2;
            a3 += w4.w * d3 * d3;
        }
        acc += (a0 + a1) + (a2 + a3);
    }

    const float bsum = block_reduce_256(acc);
    if (t == 0) partial[blockIdx.x] = bsum;
}

__global__ __launch_bounds__(TPB) void finalize_kernel(
        const float* __restrict__ partial,
        float* __restrict__ out)
{
    float v = 0.f;
    for (int idx = threadIdx.x; idx < NBLK; idx += TPB) v += partial[idx];
    const float s = block_reduce_256(v);
    if (threadIdx.x == 0) out[0] = s * SCALE_S;
}

extern "C" void kernel_launch(void* const* d_in, const int* in_sizes, int n_in,
                              void* d_out, int out_size, void* d_ws, size_t ws_size,
                              hipStream_t stream) {
    const float* outp = (const float*)d_in[0];   // output (512,512)
    const float* targ = (const float*)d_in[1];   // target (512,512)
    const float* w    = (const float*)d_in[2];   // w_ij (440,492,492)
    const float* bias = (const float*)d_in[3];   // bias (440,)

    float* partial = (float*)d_ws;               // NBLK partials

    main_kernel<<<NBLK, TPB, 0, stream>>>(outp, targ, w, bias, partial);
    finalize_kernel<<<1, TPB, 0, stream>>>(partial, (float*)d_out);
}